// Round 1
// 175.674 us; speedup vs baseline: 1.0415x; 1.0415x over previous
//
#include <hip/hip_runtime.h>
#include <math.h>

#define B_  2
#define T_  2048
#define D_  1024
#define H_  16
#define HS_ 64
#define M_  (B_*T_)   // 4096

typedef __bf16 bf16x8 __attribute__((ext_vector_type(8)));
typedef float  f32x4  __attribute__((ext_vector_type(4)));
typedef unsigned short u16;

// native HW cvt (v_cvt_pk_bf16_f32 when paired) — RNE, 1 inst vs 3-4 manual
static __device__ __forceinline__ u16 f2bf(float f) {
    __bf16 h = (__bf16)f;
    return *reinterpret_cast<u16*>(&h);
}

// async global->LDS, 16B/lane; LDS dest is lane-linear (base + lane*16).
static __device__ __forceinline__ void glds16(const u16* g, u16* l) {
    __builtin_amdgcn_global_load_lds(
        (const __attribute__((address_space(1))) void*)g,
        (__attribute__((address_space(3))) void*)l, 16, 0, 0);
}

// ---------------- fused prep: cast x, transpose+cast both weights ----------
__global__ __launch_bounds__(256) void prep_kernel(
    const float* __restrict__ x, const float* __restrict__ w_qkv,
    const float* __restrict__ w_out,
    u16* __restrict__ Xb, u16* __restrict__ WqkvT, u16* __restrict__ WoutT)
{
    int bid = blockIdx.x;
    if (bid < 4096) {                       // cast x
        int i = (bid * 256 + threadIdx.x) * 4;
        float4 v = *reinterpret_cast<const float4*>(x + i);
        ushort4 o;
        o.x = f2bf(v.x); o.y = f2bf(v.y); o.z = f2bf(v.z); o.w = f2bf(v.w);
        *reinterpret_cast<ushort4*>(Xb + i) = o;
        return;
    }
    const float* in; u16* out; int C; int c0, r0;
    if (bid < 4096 + 3072) {                // w_qkv (D x 3D) -> (3D x D)
        int t = bid - 4096;
        in = w_qkv; out = WqkvT; C = 3 * D_;
        c0 = (t % 96) * 32; r0 = (t / 96) * 32;
    } else {                                // w_out (D x D) -> (D x D)
        int t = bid - 7168;
        in = w_out; out = WoutT; C = D_;
        c0 = (t & 31) * 32; r0 = (t >> 5) * 32;
    }
    __shared__ float tile[32][33];
    int tr = threadIdx.x >> 3, tc4 = (threadIdx.x & 7) * 4;
    float4 v = *reinterpret_cast<const float4*>(in + (size_t)(r0 + tr) * C + c0 + tc4);
    tile[tr][tc4+0] = v.x; tile[tr][tc4+1] = v.y;
    tile[tr][tc4+2] = v.z; tile[tr][tc4+3] = v.w;
    __syncthreads();
    ushort4 o;
    o.x = f2bf(tile[tc4+0][tr]); o.y = f2bf(tile[tc4+1][tr]);
    o.z = f2bf(tile[tc4+2][tr]); o.w = f2bf(tile[tc4+3][tr]);
    *reinterpret_cast<ushort4*>(out + (size_t)(c0 + tr) * D_ + r0 + tc4) = o;
}

// ---------------- GEMM v2: C(MxN) = A(MxK) @ Bt(NxK)^T + bias --------------
// T3+T4 structure: BK=64, double-buffered LDS, tile t+2 prefetch issued
// mid-iteration, counted s_waitcnt vmcnt(8) (never drain-to-0 in main loop),
// raw s_barrier (no __syncthreads vmcnt(0) drain), setprio(1) around MFMA.
// LDS layout per tile: [row][8 chunk-slots of 16B], chunk c of row r at slot
// c ^ (r&7) — conflict-free for the frag read pattern (same involution as the
// proven BK=32 swizzle, extended to 8 chunks). global_load_lds writes
// lane-linear, so the swizzle is applied via the inverse-permuted global src.
template<int MODE, int BM, int BN, int WM, int WN, int NTH>
__global__ __launch_bounds__(NTH, 2) void gemm_bt2(
    const u16* __restrict__ A, const u16* __restrict__ Bt,
    const float* __restrict__ bias,
    float* __restrict__ Cf,
    u16* __restrict__ Qb, u16* __restrict__ Kb, u16* __restrict__ Vt,
    int M, int N, int K)
{
    constexpr int MF  = BM / WM / 16;     // M-frags per wave
    constexpr int NF  = BN / WN / 16;     // N-frags per wave
    constexpr int NLA = BM * 8 / NTH;     // A 16B-chunk loads per thread per tile
    constexpr int NLB = BN * 8 / NTH;

    __shared__ u16 As[2][BM * 64];        // QKV: 2x32KB; OUT: 2x16KB
    __shared__ u16 Bs[2][BN * 64];

    const int tid  = threadIdx.x;
    const int lane = tid & 63, wave = tid >> 6;
    const int wm = wave / WN, wn = wave % WN;
    const int quad = lane >> 4, lr = lane & 15, x7 = lane & 7;
    const int bm = blockIdx.x, bn = blockIdx.y;

    const u16* Ab = A  + (size_t)(bm * BM) * K;
    const u16* Bb = Bt + (size_t)(bn * BN) * K;

    // per-thread stage pointers (inverse chunk-swizzle on global source)
    const u16* srcA[NLA]; int dA[NLA];
    const u16* srcB[NLB]; int dB[NLB];
    #pragma unroll
    for (int j = 0; j < NLA; ++j) {
        int ci = j * NTH + tid, r = ci >> 3, c = (ci & 7) ^ (r & 7);
        srcA[j] = Ab + (size_t)r * K + c * 8;
        dA[j] = ci * 8;
    }
    #pragma unroll
    for (int j = 0; j < NLB; ++j) {
        int ci = j * NTH + tid, r = ci >> 3, c = (ci & 7) ^ (r & 7);
        srcB[j] = Bb + (size_t)r * K + c * 8;
        dB[j] = ci * 8;
    }

    // loop-invariant LDS read bases (u16 elements); frag i adds i*1024
    const int eA0 = (wm*(BM/WM) + lr)*64 + ((quad    ) ^ x7)*8;   // k 0..31
    const int eA1 = (wm*(BM/WM) + lr)*64 + ((quad | 4) ^ x7)*8;   // k 32..63
    const int eB0 = (wn*(BN/WN) + lr)*64 + ((quad    ) ^ x7)*8;
    const int eB1 = (wn*(BN/WN) + lr)*64 + ((quad | 4) ^ x7)*8;

    f32x4 acc[MF][NF] = {};
    const int NT = K >> 6;

    // prologue: stage tiles 0 and 1; wait tile0 landed (tile1 stays in flight)
    #pragma unroll
    for (int j = 0; j < NLA; ++j) glds16(srcA[j], &As[0][dA[j]]);
    #pragma unroll
    for (int j = 0; j < NLB; ++j) glds16(srcB[j], &Bs[0][dB[j]]);
    #pragma unroll
    for (int j = 0; j < NLA; ++j) glds16(srcA[j] + 64, &As[1][dA[j]]);
    #pragma unroll
    for (int j = 0; j < NLB; ++j) glds16(srcB[j] + 64, &Bs[1][dB[j]]);
    asm volatile("s_waitcnt vmcnt(8)" ::: "memory");
    __builtin_amdgcn_s_barrier();

    for (int t = 0; t < NT; ++t) {
        const u16* Ac = As[t & 1];
        const u16* Bc = Bs[t & 1];
        bf16x8 a[MF], b[NF];

        // phase 0: k 0..31
        #pragma unroll
        for (int i = 0; i < MF; ++i)
            a[i] = *reinterpret_cast<const bf16x8*>(Ac + eA0 + i*1024);
        #pragma unroll
        for (int j = 0; j < NF; ++j)
            b[j] = *reinterpret_cast<const bf16x8*>(Bc + eB0 + j*1024);
        __builtin_amdgcn_s_setprio(1);
        #pragma unroll
        for (int i = 0; i < MF; ++i)
            #pragma unroll
            for (int j = 0; j < NF; ++j)
                acc[i][j] = __builtin_amdgcn_mfma_f32_16x16x32_bf16(a[i], b[j], acc[i][j], 0, 0, 0);
        __builtin_amdgcn_s_setprio(0);

        // phase 1 reads: k 32..63 — after these, buf[t&1] is fully consumed
        #pragma unroll
        for (int i = 0; i < MF; ++i)
            a[i] = *reinterpret_cast<const bf16x8*>(Ac + eA1 + i*1024);
        #pragma unroll
        for (int j = 0; j < NF; ++j)
            b[j] = *reinterpret_cast<const bf16x8*>(Bc + eB1 + j*1024);
        asm volatile("s_waitcnt lgkmcnt(0)" ::: "memory");   // my reads done
        __builtin_amdgcn_s_barrier();                        // everyone's done

        // stage tile t+2 into the buffer we just finished reading
        if (t + 2 < NT) {
            const int k0 = (t + 2) << 6;
            u16* Ad = As[t & 1]; u16* Bd = Bs[t & 1];
            #pragma unroll
            for (int j = 0; j < NLA; ++j) glds16(srcA[j] + k0, Ad + dA[j]);
            #pragma unroll
            for (int j = 0; j < NLB; ++j) glds16(srcB[j] + k0, Bd + dB[j]);
        }

        __builtin_amdgcn_s_setprio(1);
        #pragma unroll
        for (int i = 0; i < MF; ++i)
            #pragma unroll
            for (int j = 0; j < NF; ++j)
                acc[i][j] = __builtin_amdgcn_mfma_f32_16x16x32_bf16(a[i], b[j], acc[i][j], 0, 0, 0);
        __builtin_amdgcn_s_setprio(0);

        // retire tile t+1 (8 oldest); tile t+2's 8 stay in flight.
        if (t + 2 < NT) { asm volatile("s_waitcnt vmcnt(8)" ::: "memory"); }
        else           { asm volatile("s_waitcnt vmcnt(0)" ::: "memory"); }
        __builtin_amdgcn_s_barrier();
    }

    // -------- epilogue --------
    #pragma unroll
    for (int i = 0; i < MF; ++i) {
        int m0 = bm*BM + wm*(BM/WM) + i*16 + quad*4;   // 4-aligned
        #pragma unroll
        for (int j = 0; j < NF; ++j) {
            int ncol = bn*BN + wn*(BN/WN) + j*16 + lr;
            float bv = bias[ncol];
            float v4[4];
            #pragma unroll
            for (int r = 0; r < 4; ++r) v4[r] = acc[i][j][r] + bv;
            if (MODE == 1) {
                #pragma unroll
                for (int r = 0; r < 4; ++r)
                    Cf[(size_t)(m0 + r) * N + ncol] = v4[r];
            } else {
                int bb = m0 >> 11, t0 = m0 & (T_ - 1);
                int s = ncol >> 10, rem = ncol & 1023;
                int h = rem >> 6, d = rem & 63;
                int bh = bb * H_ + h;
                if (s == 0) {
                    // fold softmax scale AND log2(e) (attn uses exp2): 0.125*log2e
                    #pragma unroll
                    for (int r = 0; r < 4; ++r)
                        Qb[((size_t)bh*T_ + t0 + r)*HS_ + d] = f2bf(v4[r] * 0.1803368801111244f);
                } else if (s == 1) {
                    #pragma unroll
                    for (int r = 0; r < 4; ++r)
                        Kb[((size_t)bh*T_ + t0 + r)*HS_ + d] = f2bf(v4[r]);
                } else {
                    ushort4 o;   // consecutive t -> one 8B store
                    o.x = f2bf(v4[0]); o.y = f2bf(v4[1]);
                    o.z = f2bf(v4[2]); o.w = f2bf(v4[3]);
                    *reinterpret_cast<ushort4*>(&Vt[((size_t)bh*HS_ + d)*T_ + t0]) = o;
                }
            }
        }
    }
}

// ---------------- Flash attention (causal), bf16 MFMA ----------------
// 1024 blocks x 256 thr. Unchanged this round (not top dispatch).
__global__ __launch_bounds__(256) void attn_kernel(
    const u16* __restrict__ Qb, const u16* __restrict__ Kb,
    const u16* __restrict__ Vt, u16* __restrict__ Ob)
{
    __shared__ u16 Ks[64 * 64];        // [key][d], swizzled chunks, 8 KB
    __shared__ u16 Vs[64 * 64];        // [d][key], swizzled chunks, 8 KB
    __shared__ u16 Ps[4][16 * 64];     // per-wave P (16 q x 64 key), swizzled

    int tid  = threadIdx.x;
    int lane = tid & 63, wave = tid >> 6;          // wave 0..3
    int quad = lane >> 4, lr = lane & 15;

    int lin = blockIdx.x;                          // 1024 blocks
    int bh  = (lin & 7) + 8 * ((lin >> 3) & 3);    // XCD-local bh
    int idx = lin >> 5;                            // 0..31
    int qt  = idx < 16 ? idx : 47 - idx;           // balanced pair mapping
    int qw  = qt * 64 + wave * 16;                 // wave's 16 query rows

    // Q fragments (A-layout); 1/sqrt(HS)*log2e pre-folded upstream
    const u16* Qp = Qb + ((size_t)bh * T_ + qw) * HS_;
    bf16x8 qf[2];
    #pragma unroll
    for (int h2 = 0; h2 < 2; ++h2)
        qf[h2] = *reinterpret_cast<const bf16x8*>(Qp + lr*HS_ + h2*32 + quad*8);

    f32x4 Oa[4] = {};
    float lrow[4] = {0.f, 0.f, 0.f, 0.f};

    // ---- loop-invariant LDS addresses (u16-element offsets) ----
    int e      = quad ^ (lr & 7);
    int rb0    = (lr * 8 + e) * 8;          // kk=0 base (chunk-slot*8 u16)
    int rb1    = (lr * 8 + (e ^ 4)) * 8;    // kk=1 base
    int offw[4][4];
    #pragma unroll
    for (int nt = 0; nt < 4; ++nt)
        #pragma unroll
        for (int r = 0; r < 4; ++r) {
            int prow = quad*4 + r;
            offw[nt][r] = (prow*8 + ((nt*2 + (lr >> 3)) ^ (prow & 7)))*8 + (lr & 7);
        }
    u16* Psw = Ps[wave];

    // staging: 256 thr x 2 chunks per matrix; swizzle via source redirect
    int srow = tid >> 3;
    int scol = ((tid & 7) ^ (srow & 7)) * 8;
    const u16* kp0 = Kb + ((size_t)bh*T_ + srow     )*HS_ + scol;
    const u16* kp1 = Kb + ((size_t)bh*T_ + srow + 32)*HS_ + scol;
    const u16* vp0 = Vt + ((size_t)bh*HS_ + srow     )*T_ + scol;
    const u16* vp1 = Vt + ((size_t)bh*HS_ + srow + 32)*T_ + scol;

    bf16x8 kpre0 = *reinterpret_cast<const bf16x8*>(kp0);
    bf16x8 kpre1 = *reinterpret_cast<const bf16x8*>(kp1);
    bf16x8 vpre0 = *reinterpret_cast<const bf16x8*>(vp0);
    bf16x8 vpre1 = *reinterpret_cast<const bf16x8*>(vp1);

    for (int jt = 0; jt <= qt; ++jt) {
        __syncthreads();
        reinterpret_cast<bf16x8*>(Ks)[tid]       = kpre0;
        reinterpret_cast<bf16x8*>(Ks)[tid + 256] = kpre1;
        reinterpret_cast<bf16x8*>(Vs)[tid]       = vpre0;
        reinterpret_cast<bf16x8*>(Vs)[tid + 256] = vpre1;
        if (jt < qt) {
            kp0 += 64*HS_; kp1 += 64*HS_; vp0 += 64; vp1 += 64;
            kpre0 = *reinterpret_cast<const bf16x8*>(kp0);
            kpre1 = *reinterpret_cast<const bf16x8*>(kp1);
            vpre0 = *reinterpret_cast<const bf16x8*>(vp0);
            vpre1 = *reinterpret_cast<const bf16x8*>(vp1);
        }
        __syncthreads();

        // S = Q @ K^T
        f32x4 Sa[4] = {};
        #pragma unroll
        for (int nt = 0; nt < 4; ++nt) {
            bf16x8 bk0 = *reinterpret_cast<const bf16x8*>(Ks + rb0 + nt*1024);
            bf16x8 bk1 = *reinterpret_cast<const bf16x8*>(Ks + rb1 + nt*1024);
            Sa[nt] = __builtin_amdgcn_mfma_f32_16x16x32_bf16(qf[0], bk0, Sa[nt], 0, 0, 0);
            Sa[nt] = __builtin_amdgcn_mfma_f32_16x16x32_bf16(qf[1], bk1, Sa[nt], 0, 0, 0);
        }

        if (jt == qt) {   // causal mask in diagonal tile
            int kb = jt * 64;
            #pragma unroll
            for (int nt = 0; nt < 4; ++nt)
                #pragma unroll
                for (int r = 0; r < 4; ++r) {
                    int kg = kb + nt*16 + lr;
                    int qg = qw + quad*4 + r;
                    if (kg > qg) Sa[nt][r] = -INFINITY;
                }
        }

        // P = exp2(S); per-lane row sums; P -> LDS
        #pragma unroll
        for (int nt = 0; nt < 4; ++nt)
            #pragma unroll
            for (int r = 0; r < 4; ++r) {
                float pv = __builtin_amdgcn_exp2f(Sa[nt][r]);
                lrow[r] += pv;
                Psw[offw[nt][r]] = f2bf(pv);
            }

        // O += P @ V  (same-wave LDS ordering via lgkmcnt; no barrier)
        #pragma unroll
        for (int kk = 0; kk < 2; ++kk) {
            int rb = kk ? rb1 : rb0;
            bf16x8 pa = *reinterpret_cast<const bf16x8*>(Psw + rb);
            #pragma unroll
            for (int nt = 0; nt < 4; ++nt) {
                bf16x8 vb = *reinterpret_cast<const bf16x8*>(Vs + rb + nt*1024);
                Oa[nt] = __builtin_amdgcn_mfma_f32_16x16x32_bf16(pa, vb, Oa[nt], 0, 0, 0);
            }
        }
    }

    // epilogue: reduce row sums across 16 col-lanes, normalize, store
    int b = bh >> 4, h = bh & 15;
    #pragma unroll
    for (int r = 0; r < 4; ++r) {
        float s = lrow[r];
        #pragma unroll
        for (int off = 8; off >= 1; off >>= 1)
            s += __shfl_xor(s, off, 64);
        float inv = 1.f / s;
        int qg = qw + quad*4 + r;
        #pragma unroll
        for (int nt = 0; nt < 4; ++nt) {
            int d = nt*16 + lr;
            Ob[((size_t)b*T_ + qg)*D_ + h*HS_ + d] = f2bf(Oa[nt][r] * inv);
        }
    }
}

extern "C" void kernel_launch(void* const* d_in, const int* in_sizes, int n_in,
                              void* d_out, int out_size, void* d_ws, size_t ws_size,
                              hipStream_t stream) {
    (void)in_sizes; (void)n_in; (void)out_size; (void)ws_size;
    const float* x     = (const float*)d_in[0];
    const float* w_qkv = (const float*)d_in[1];
    const float* b_qkv = (const float*)d_in[2];
    const float* w_out = (const float*)d_in[3];
    const float* b_out = (const float*)d_in[4];
    float* out = (float*)d_out;

    char* ws = (char*)d_ws;
    u16* Xb    = (u16*)ws; ws += (size_t)M_ * D_ * 2;
    u16* WqkvT = (u16*)ws; ws += (size_t)3 * D_ * D_ * 2;
    u16* WoutT = (u16*)ws; ws += (size_t)D_ * D_ * 2;
    u16* Qb    = (u16*)ws; ws += (size_t)M_ * D_ * 2;
    u16* Kb    = (u16*)ws; ws += (size_t)M_ * D_ * 2;
    u16* Vt    = (u16*)ws; ws += (size_t)M_ * D_ * 2;
    u16* Ob    = (u16*)ws; ws += (size_t)M_ * D_ * 2;

    prep_kernel<<<8192, 256, 0, stream>>>(x, w_qkv, w_out, Xb, WqkvT, WoutT);
    // QKV: 256x256 tile, 8 waves (2Mx4N), 192 blocks
    gemm_bt2<0, 256, 256, 2, 4, 512><<<dim3(M_/256, 3*D_/256), 512, 0, stream>>>(
        Xb, WqkvT, b_qkv, nullptr, Qb, Kb, Vt, M_, 3*D_, D_);
    attn_kernel<<<1024, 256, 0, stream>>>(Qb, Kb, Vt, Ob);
    // out-proj: 128x128 tile, 4 waves (2Mx2N), 256 blocks — pipeline hides
    // the per-tile load latency this 1-block/CU kernel previously ate raw
    gemm_bt2<1, 128, 128, 2, 2, 256><<<dim3(M_/128, D_/128), 256, 0, stream>>>(
        Ob, WoutT, b_out, out, nullptr, nullptr, nullptr, M_, D_, D_);
}

// Round 2
// 174.130 us; speedup vs baseline: 1.0508x; 1.0089x over previous
//
#include <hip/hip_runtime.h>
#include <math.h>

#define B_  2
#define T_  2048
#define D_  1024
#define H_  16
#define HS_ 64
#define M_  (B_*T_)   // 4096

typedef __bf16 bf16x8 __attribute__((ext_vector_type(8)));
typedef float  f32x4  __attribute__((ext_vector_type(4)));
typedef unsigned short u16;

// native HW cvt (v_cvt_pk_bf16_f32 when paired) — RNE, 1 inst vs 3-4 manual
static __device__ __forceinline__ u16 f2bf(float f) {
    __bf16 h = (__bf16)f;
    return *reinterpret_cast<u16*>(&h);
}

// async global->LDS, 16B/lane; LDS dest is lane-linear (base + lane*16).
static __device__ __forceinline__ void glds16(const u16* g, u16* l) {
    __builtin_amdgcn_global_load_lds(
        (const __attribute__((address_space(1))) void*)g,
        (__attribute__((address_space(3))) void*)l, 16, 0, 0);
}

// ---------------- fused prep: cast x, transpose+cast both weights ----------
__global__ __launch_bounds__(256) void prep_kernel(
    const float* __restrict__ x, const float* __restrict__ w_qkv,
    const float* __restrict__ w_out,
    u16* __restrict__ Xb, u16* __restrict__ WqkvT, u16* __restrict__ WoutT)
{
    int bid = blockIdx.x;
    if (bid < 4096) {                       // cast x
        int i = (bid * 256 + threadIdx.x) * 4;
        float4 v = *reinterpret_cast<const float4*>(x + i);
        ushort4 o;
        o.x = f2bf(v.x); o.y = f2bf(v.y); o.z = f2bf(v.z); o.w = f2bf(v.w);
        *reinterpret_cast<ushort4*>(Xb + i) = o;
        return;
    }
    const float* in; u16* out; int C; int c0, r0;
    if (bid < 4096 + 3072) {                // w_qkv (D x 3D) -> (3D x D)
        int t = bid - 4096;
        in = w_qkv; out = WqkvT; C = 3 * D_;
        c0 = (t % 96) * 32; r0 = (t / 96) * 32;
    } else {                                // w_out (D x D) -> (D x D)
        int t = bid - 7168;
        in = w_out; out = WoutT; C = D_;
        c0 = (t & 31) * 32; r0 = (t >> 5) * 32;
    }
    __shared__ float tile[32][33];
    int tr = threadIdx.x >> 3, tc4 = (threadIdx.x & 7) * 4;
    float4 v = *reinterpret_cast<const float4*>(in + (size_t)(r0 + tr) * C + c0 + tc4);
    tile[tr][tc4+0] = v.x; tile[tr][tc4+1] = v.y;
    tile[tr][tc4+2] = v.z; tile[tr][tc4+3] = v.w;
    __syncthreads();
    ushort4 o;
    o.x = f2bf(tile[tc4+0][tr]); o.y = f2bf(tile[tc4+1][tr]);
    o.z = f2bf(tile[tc4+2][tr]); o.w = f2bf(tile[tc4+3][tr]);
    *reinterpret_cast<ushort4*>(out + (size_t)(c0 + tr) * D_ + r0 + tc4) = o;
}

// ---------------- QKV GEMM: m201-style 4-phase-per-K-tile pipeline ---------
// 256x256 tile, BK=64, 8 waves (2M x 4N), 512 thr, 128 KiB LDS (2 dbuf).
// Per buffer: 4 regions {A,B} x {k-half}, each 256 rows x 32 k (16 KB),
// chunk swizzle slot = c ^ ((r>>1)&3) (proven conflict-free in R0).
// Per K-tile, 4 phases:
//   A: ds a[0..3]k0 + b[0..3]k0 (8) | stage A-k0[t+1] | bar | lgkm0 | 16 MFMA | bar
//   B: ds a[4..7]k0 (4)            | stage B-k0[t+1] | bar | lgkm0 | 16 MFMA | vmcnt(4) | bar
//   C: ds a[0..3]k1 + b[0..3]k1 (8)| stage A-k1[t+1] | bar | lgkm0 | 16 MFMA | bar
//   D: ds a[4..7]k1 (4)            | stage B-k1[t+1] | bar | lgkm0 | 16 MFMA | vmcnt(4) | bar
// Staging targets the OPPOSITE buffer (tile t+1); each region's last reader
// is >=2 barriers upstream. vmcnt(4) retires exactly the 2 regions consumed
// 2 phases later; 8 loads stay in flight — never drained in the main loop.
__global__ __launch_bounds__(512, 2) void gemm_qkv(
    const u16* __restrict__ A, const u16* __restrict__ Bt,
    const float* __restrict__ bias,
    u16* __restrict__ Qb, u16* __restrict__ Kb, u16* __restrict__ Vt)
{
    constexpr int K  = D_;        // 1024
    constexpr int NT = K / 64;    // 16

    __shared__ u16 LDS[2][2][2][8192];  // [buf][A|B][khalf][256r x 32k swz] = 128 KiB

    const int tid  = threadIdx.x;
    const int lane = tid & 63, wave = tid >> 6;
    const int wm = wave >> 2, wn = wave & 3;       // 2 x 4
    const int quad = lane >> 4, lr = lane & 15;
    const int bm = blockIdx.x, bn = blockIdx.y;

    const u16* Ab = A  + (size_t)(bm * 256) * K;
    const u16* Bb = Bt + (size_t)(bn * 256) * K;

    // staging: thread covers chunk-indices {tid, tid+512} of each 1024-chunk
    // region; inverse swizzle applied on the global source (LDS dest linear).
    const int r0 = tid >> 2;
    const int c0 = (tid & 3) ^ ((tid >> 3) & 3);
    const u16* sA0 = Ab + (size_t)r0 * K + c0 * 8;
    const u16* sA1 = sA0 + (size_t)128 * K;
    const u16* sB0 = Bb + (size_t)r0 * K + c0 * 8;
    const u16* sB1 = sB0 + (size_t)128 * K;
    const int d0 = tid * 8, d1 = (tid + 512) * 8;

    // loop-invariant read bases (u16 elems); frag i adds i*512
    const int swz = (lr >> 1) & 3;
    const int eA = ((wm*128 + lr) * 4 + (quad ^ swz)) * 8;
    const int eB = ((wn*64  + lr) * 4 + (quad ^ swz)) * 8;

    f32x4 acc[8][4] = {};

#define STG(mat, kh, tt) do { \
        u16* _d = &LDS[(tt) & 1][mat][kh][0]; \
        const int _ko = (tt) * 64 + (kh) * 32; \
        glds16(((mat) ? sB0 : sA0) + _ko, _d + d0); \
        glds16(((mat) ? sB1 : sA1) + _ko, _d + d1); \
    } while (0)

#define MFMA_QUAD(mh) do { \
        __builtin_amdgcn_s_setprio(1); \
        _Pragma("unroll") \
        for (int i_ = 0; i_ < 4; ++i_) \
            _Pragma("unroll") \
            for (int j_ = 0; j_ < 4; ++j_) \
                acc[(mh)*4 + i_][j_] = __builtin_amdgcn_mfma_f32_16x16x32_bf16( \
                    a[i_], b[j_], acc[(mh)*4 + i_][j_], 0, 0, 0); \
        __builtin_amdgcn_s_setprio(0); \
    } while (0)

    // prologue: tile 0 regions in consumption order; keep A-k1/B-k1 in flight
    STG(0,0,0); STG(1,0,0); STG(0,1,0); STG(1,1,0);
    asm volatile("s_waitcnt vmcnt(4)" ::: "memory");
    __builtin_amdgcn_s_barrier();

    for (int t = 0; t < NT; ++t) {
        const int cb = t & 1;
        const bool last = (t == NT - 1);
        const u16* Ar0 = &LDS[cb][0][0][0];
        const u16* Ar1 = &LDS[cb][0][1][0];
        const u16* Br0 = &LDS[cb][1][0][0];
        const u16* Br1 = &LDS[cb][1][1][0];
        bf16x8 a[4], b[4];

        // ---- phase A: k0, m-frags 0-3 (+ b k0) ----
        #pragma unroll
        for (int i = 0; i < 4; ++i) a[i] = *reinterpret_cast<const bf16x8*>(Ar0 + eA + i*512);
        #pragma unroll
        for (int j = 0; j < 4; ++j) b[j] = *reinterpret_cast<const bf16x8*>(Br0 + eB + j*512);
        if (!last) STG(0,0,t+1);
        __builtin_amdgcn_s_barrier();
        asm volatile("s_waitcnt lgkmcnt(0)" ::: "memory");
        MFMA_QUAD(0);
        __builtin_amdgcn_s_barrier();

        // ---- phase B: k0, m-frags 4-7 (b reused) ----
        #pragma unroll
        for (int i = 0; i < 4; ++i) a[i] = *reinterpret_cast<const bf16x8*>(Ar0 + eA + (i+4)*512);
        if (!last) STG(1,0,t+1);
        __builtin_amdgcn_s_barrier();
        asm volatile("s_waitcnt lgkmcnt(0)" ::: "memory");
        MFMA_QUAD(1);
        if (!last) { asm volatile("s_waitcnt vmcnt(4)" ::: "memory"); }
        else       { asm volatile("s_waitcnt vmcnt(0)" ::: "memory"); }
        __builtin_amdgcn_s_barrier();

        // ---- phase C: k1, m-frags 0-3 (+ b k1) ----
        #pragma unroll
        for (int i = 0; i < 4; ++i) a[i] = *reinterpret_cast<const bf16x8*>(Ar1 + eA + i*512);
        #pragma unroll
        for (int j = 0; j < 4; ++j) b[j] = *reinterpret_cast<const bf16x8*>(Br1 + eB + j*512);
        if (!last) STG(0,1,t+1);
        __builtin_amdgcn_s_barrier();
        asm volatile("s_waitcnt lgkmcnt(0)" ::: "memory");
        MFMA_QUAD(0);
        __builtin_amdgcn_s_barrier();

        // ---- phase D: k1, m-frags 4-7 ----
        #pragma unroll
        for (int i = 0; i < 4; ++i) a[i] = *reinterpret_cast<const bf16x8*>(Ar1 + eA + (i+4)*512);
        if (!last) STG(1,1,t+1);
        __builtin_amdgcn_s_barrier();
        asm volatile("s_waitcnt lgkmcnt(0)" ::: "memory");
        MFMA_QUAD(1);
        asm volatile("s_waitcnt vmcnt(4)" ::: "memory");  // retire A-k0/B-k0[t+1]
        __builtin_amdgcn_s_barrier();
    }
#undef STG
#undef MFMA_QUAD

    // -------- epilogue: scatter to Q (scale folded) / K / V^T --------
    #pragma unroll
    for (int i = 0; i < 8; ++i) {
        int m0 = bm*256 + wm*128 + i*16 + quad*4;   // 4-aligned
        #pragma unroll
        for (int j = 0; j < 4; ++j) {
            int ncol = bn*256 + wn*64 + j*16 + lr;
            float bv = bias[ncol];
            float v4[4];
            #pragma unroll
            for (int r = 0; r < 4; ++r) v4[r] = acc[i][j][r] + bv;
            int bb = m0 >> 11, t0 = m0 & (T_ - 1);
            int s = ncol >> 10, rem = ncol & 1023;
            int h = rem >> 6, d = rem & 63;
            int bh = bb * H_ + h;
            if (s == 0) {
                // fold softmax scale AND log2(e) (attn uses exp2): 0.125*log2e
                #pragma unroll
                for (int r = 0; r < 4; ++r)
                    Qb[((size_t)bh*T_ + t0 + r)*HS_ + d] = f2bf(v4[r] * 0.1803368801111244f);
            } else if (s == 1) {
                #pragma unroll
                for (int r = 0; r < 4; ++r)
                    Kb[((size_t)bh*T_ + t0 + r)*HS_ + d] = f2bf(v4[r]);
            } else {
                ushort4 o;   // consecutive t -> one 8B store
                o.x = f2bf(v4[0]); o.y = f2bf(v4[1]);
                o.z = f2bf(v4[2]); o.w = f2bf(v4[3]);
                *reinterpret_cast<ushort4*>(&Vt[((size_t)bh*HS_ + d)*T_ + t0]) = o;
            }
        }
    }
}

// ---------------- out-proj GEMM (round-1 structure, unchanged) -------------
template<int MODE, int BM, int BN, int WM, int WN, int NTH>
__global__ __launch_bounds__(NTH, 2) void gemm_bt2(
    const u16* __restrict__ A, const u16* __restrict__ Bt,
    const float* __restrict__ bias,
    float* __restrict__ Cf,
    int M, int N, int K)
{
    constexpr int MF  = BM / WM / 16;
    constexpr int NF  = BN / WN / 16;
    constexpr int NLA = BM * 8 / NTH;
    constexpr int NLB = BN * 8 / NTH;

    __shared__ u16 As[2][BM * 64];
    __shared__ u16 Bs[2][BN * 64];

    const int tid  = threadIdx.x;
    const int lane = tid & 63, wave = tid >> 6;
    const int wm = wave / WN, wn = wave % WN;
    const int quad = lane >> 4, lr = lane & 15, x7 = lane & 7;
    const int bm = blockIdx.x, bn = blockIdx.y;

    const u16* Ab = A  + (size_t)(bm * BM) * K;
    const u16* Bb = Bt + (size_t)(bn * BN) * K;

    const u16* srcA[NLA]; int dA[NLA];
    const u16* srcB[NLB]; int dB[NLB];
    #pragma unroll
    for (int j = 0; j < NLA; ++j) {
        int ci = j * NTH + tid, r = ci >> 3, c = (ci & 7) ^ (r & 7);
        srcA[j] = Ab + (size_t)r * K + c * 8;
        dA[j] = ci * 8;
    }
    #pragma unroll
    for (int j = 0; j < NLB; ++j) {
        int ci = j * NTH + tid, r = ci >> 3, c = (ci & 7) ^ (r & 7);
        srcB[j] = Bb + (size_t)r * K + c * 8;
        dB[j] = ci * 8;
    }

    const int eA0 = (wm*(BM/WM) + lr)*64 + ((quad    ) ^ x7)*8;
    const int eA1 = (wm*(BM/WM) + lr)*64 + ((quad | 4) ^ x7)*8;
    const int eB0 = (wn*(BN/WN) + lr)*64 + ((quad    ) ^ x7)*8;
    const int eB1 = (wn*(BN/WN) + lr)*64 + ((quad | 4) ^ x7)*8;

    f32x4 acc[MF][NF] = {};
    const int NT = K >> 6;

    #pragma unroll
    for (int j = 0; j < NLA; ++j) glds16(srcA[j], &As[0][dA[j]]);
    #pragma unroll
    for (int j = 0; j < NLB; ++j) glds16(srcB[j], &Bs[0][dB[j]]);
    #pragma unroll
    for (int j = 0; j < NLA; ++j) glds16(srcA[j] + 64, &As[1][dA[j]]);
    #pragma unroll
    for (int j = 0; j < NLB; ++j) glds16(srcB[j] + 64, &Bs[1][dB[j]]);
    asm volatile("s_waitcnt vmcnt(8)" ::: "memory");
    __builtin_amdgcn_s_barrier();

    for (int t = 0; t < NT; ++t) {
        const u16* Ac = As[t & 1];
        const u16* Bc = Bs[t & 1];
        bf16x8 a[MF], b[NF];

        #pragma unroll
        for (int i = 0; i < MF; ++i)
            a[i] = *reinterpret_cast<const bf16x8*>(Ac + eA0 + i*1024);
        #pragma unroll
        for (int j = 0; j < NF; ++j)
            b[j] = *reinterpret_cast<const bf16x8*>(Bc + eB0 + j*1024);
        __builtin_amdgcn_s_setprio(1);
        #pragma unroll
        for (int i = 0; i < MF; ++i)
            #pragma unroll
            for (int j = 0; j < NF; ++j)
                acc[i][j] = __builtin_amdgcn_mfma_f32_16x16x32_bf16(a[i], b[j], acc[i][j], 0, 0, 0);
        __builtin_amdgcn_s_setprio(0);

        #pragma unroll
        for (int i = 0; i < MF; ++i)
            a[i] = *reinterpret_cast<const bf16x8*>(Ac + eA1 + i*1024);
        #pragma unroll
        for (int j = 0; j < NF; ++j)
            b[j] = *reinterpret_cast<const bf16x8*>(Bc + eB1 + j*1024);
        asm volatile("s_waitcnt lgkmcnt(0)" ::: "memory");
        __builtin_amdgcn_s_barrier();

        if (t + 2 < NT) {
            const int k0 = (t + 2) << 6;
            u16* Ad = As[t & 1]; u16* Bd = Bs[t & 1];
            #pragma unroll
            for (int j = 0; j < NLA; ++j) glds16(srcA[j] + k0, Ad + dA[j]);
            #pragma unroll
            for (int j = 0; j < NLB; ++j) glds16(srcB[j] + k0, Bd + dB[j]);
        }

        __builtin_amdgcn_s_setprio(1);
        #pragma unroll
        for (int i = 0; i < MF; ++i)
            #pragma unroll
            for (int j = 0; j < NF; ++j)
                acc[i][j] = __builtin_amdgcn_mfma_f32_16x16x32_bf16(a[i], b[j], acc[i][j], 0, 0, 0);
        __builtin_amdgcn_s_setprio(0);

        if (t + 2 < NT) { asm volatile("s_waitcnt vmcnt(8)" ::: "memory"); }
        else           { asm volatile("s_waitcnt vmcnt(0)" ::: "memory"); }
        __builtin_amdgcn_s_barrier();
    }

    #pragma unroll
    for (int i = 0; i < MF; ++i) {
        int m0 = bm*BM + wm*(BM/WM) + i*16 + quad*4;
        #pragma unroll
        for (int j = 0; j < NF; ++j) {
            int ncol = bn*BN + wn*(BN/WN) + j*16 + lr;
            float bv = bias[ncol];
            #pragma unroll
            for (int r = 0; r < 4; ++r)
                Cf[(size_t)(m0 + r) * N + ncol] = acc[i][j][r] + bv;
        }
    }
}

// ---------------- Flash attention (causal), bf16 MFMA ----------------
// 1024 blocks x 256 thr. Unchanged this round.
__global__ __launch_bounds__(256) void attn_kernel(
    const u16* __restrict__ Qb, const u16* __restrict__ Kb,
    const u16* __restrict__ Vt, u16* __restrict__ Ob)
{
    __shared__ u16 Ks[64 * 64];        // [key][d], swizzled chunks, 8 KB
    __shared__ u16 Vs[64 * 64];        // [d][key], swizzled chunks, 8 KB
    __shared__ u16 Ps[4][16 * 64];     // per-wave P (16 q x 64 key), swizzled

    int tid  = threadIdx.x;
    int lane = tid & 63, wave = tid >> 6;          // wave 0..3
    int quad = lane >> 4, lr = lane & 15;

    int lin = blockIdx.x;                          // 1024 blocks
    int bh  = (lin & 7) + 8 * ((lin >> 3) & 3);    // XCD-local bh
    int idx = lin >> 5;                            // 0..31
    int qt  = idx < 16 ? idx : 47 - idx;           // balanced pair mapping
    int qw  = qt * 64 + wave * 16;                 // wave's 16 query rows

    // Q fragments (A-layout); 1/sqrt(HS)*log2e pre-folded upstream
    const u16* Qp = Qb + ((size_t)bh * T_ + qw) * HS_;
    bf16x8 qf[2];
    #pragma unroll
    for (int h2 = 0; h2 < 2; ++h2)
        qf[h2] = *reinterpret_cast<const bf16x8*>(Qp + lr*HS_ + h2*32 + quad*8);

    f32x4 Oa[4] = {};
    float lrow[4] = {0.f, 0.f, 0.f, 0.f};

    // ---- loop-invariant LDS addresses (u16-element offsets) ----
    int e      = quad ^ (lr & 7);
    int rb0    = (lr * 8 + e) * 8;          // kk=0 base (chunk-slot*8 u16)
    int rb1    = (lr * 8 + (e ^ 4)) * 8;    // kk=1 base
    int offw[4][4];
    #pragma unroll
    for (int nt = 0; nt < 4; ++nt)
        #pragma unroll
        for (int r = 0; r < 4; ++r) {
            int prow = quad*4 + r;
            offw[nt][r] = (prow*8 + ((nt*2 + (lr >> 3)) ^ (prow & 7)))*8 + (lr & 7);
        }
    u16* Psw = Ps[wave];

    // staging: 256 thr x 2 chunks per matrix; swizzle via source redirect
    int srow = tid >> 3;
    int scol = ((tid & 7) ^ (srow & 7)) * 8;
    const u16* kp0 = Kb + ((size_t)bh*T_ + srow     )*HS_ + scol;
    const u16* kp1 = Kb + ((size_t)bh*T_ + srow + 32)*HS_ + scol;
    const u16* vp0 = Vt + ((size_t)bh*HS_ + srow     )*T_ + scol;
    const u16* vp1 = Vt + ((size_t)bh*HS_ + srow + 32)*T_ + scol;

    bf16x8 kpre0 = *reinterpret_cast<const bf16x8*>(kp0);
    bf16x8 kpre1 = *reinterpret_cast<const bf16x8*>(kp1);
    bf16x8 vpre0 = *reinterpret_cast<const bf16x8*>(vp0);
    bf16x8 vpre1 = *reinterpret_cast<const bf16x8*>(vp1);

    for (int jt = 0; jt <= qt; ++jt) {
        __syncthreads();
        reinterpret_cast<bf16x8*>(Ks)[tid]       = kpre0;
        reinterpret_cast<bf16x8*>(Ks)[tid + 256] = kpre1;
        reinterpret_cast<bf16x8*>(Vs)[tid]       = vpre0;
        reinterpret_cast<bf16x8*>(Vs)[tid + 256] = vpre1;
        if (jt < qt) {
            kp0 += 64*HS_; kp1 += 64*HS_; vp0 += 64; vp1 += 64;
            kpre0 = *reinterpret_cast<const bf16x8*>(kp0);
            kpre1 = *reinterpret_cast<const bf16x8*>(kp1);
            vpre0 = *reinterpret_cast<const bf16x8*>(vp0);
            vpre1 = *reinterpret_cast<const bf16x8*>(vp1);
        }
        __syncthreads();

        // S = Q @ K^T
        f32x4 Sa[4] = {};
        #pragma unroll
        for (int nt = 0; nt < 4; ++nt) {
            bf16x8 bk0 = *reinterpret_cast<const bf16x8*>(Ks + rb0 + nt*1024);
            bf16x8 bk1 = *reinterpret_cast<const bf16x8*>(Ks + rb1 + nt*1024);
            Sa[nt] = __builtin_amdgcn_mfma_f32_16x16x32_bf16(qf[0], bk0, Sa[nt], 0, 0, 0);
            Sa[nt] = __builtin_amdgcn_mfma_f32_16x16x32_bf16(qf[1], bk1, Sa[nt], 0, 0, 0);
        }

        if (jt == qt) {   // causal mask in diagonal tile
            int kb = jt * 64;
            #pragma unroll
            for (int nt = 0; nt < 4; ++nt)
                #pragma unroll
                for (int r = 0; r < 4; ++r) {
                    int kg = kb + nt*16 + lr;
                    int qg = qw + quad*4 + r;
                    if (kg > qg) Sa[nt][r] = -INFINITY;
                }
        }

        // P = exp2(S); per-lane row sums; P -> LDS
        #pragma unroll
        for (int nt = 0; nt < 4; ++nt)
            #pragma unroll
            for (int r = 0; r < 4; ++r) {
                float pv = __builtin_amdgcn_exp2f(Sa[nt][r]);
                lrow[r] += pv;
                Psw[offw[nt][r]] = f2bf(pv);
            }

        // O += P @ V  (same-wave LDS ordering via lgkmcnt; no barrier)
        #pragma unroll
        for (int kk = 0; kk < 2; ++kk) {
            int rb = kk ? rb1 : rb0;
            bf16x8 pa = *reinterpret_cast<const bf16x8*>(Psw + rb);
            #pragma unroll
            for (int nt = 0; nt < 4; ++nt) {
                bf16x8 vb = *reinterpret_cast<const bf16x8*>(Vs + rb + nt*1024);
                Oa[nt] = __builtin_amdgcn_mfma_f32_16x16x32_bf16(pa, vb, Oa[nt], 0, 0, 0);
            }
        }
    }

    // epilogue: reduce row sums across 16 col-lanes, normalize, store
    int b = bh >> 4, h = bh & 15;
    #pragma unroll
    for (int r = 0; r < 4; ++r) {
        float s = lrow[r];
        #pragma unroll
        for (int off = 8; off >= 1; off >>= 1)
            s += __shfl_xor(s, off, 64);
        float inv = 1.f / s;
        int qg = qw + quad*4 + r;
        #pragma unroll
        for (int nt = 0; nt < 4; ++nt) {
            int d = nt*16 + lr;
            Ob[((size_t)b*T_ + qg)*D_ + h*HS_ + d] = f2bf(Oa[nt][r] * inv);
        }
    }
}

extern "C" void kernel_launch(void* const* d_in, const int* in_sizes, int n_in,
                              void* d_out, int out_size, void* d_ws, size_t ws_size,
                              hipStream_t stream) {
    (void)in_sizes; (void)n_in; (void)out_size; (void)ws_size;
    const float* x     = (const float*)d_in[0];
    const float* w_qkv = (const float*)d_in[1];
    const float* b_qkv = (const float*)d_in[2];
    const float* w_out = (const float*)d_in[3];
    const float* b_out = (const float*)d_in[4];
    float* out = (float*)d_out;

    char* ws = (char*)d_ws;
    u16* Xb    = (u16*)ws; ws += (size_t)M_ * D_ * 2;
    u16* WqkvT = (u16*)ws; ws += (size_t)3 * D_ * D_ * 2;
    u16* WoutT = (u16*)ws; ws += (size_t)D_ * D_ * 2;
    u16* Qb    = (u16*)ws; ws += (size_t)M_ * D_ * 2;
    u16* Kb    = (u16*)ws; ws += (size_t)M_ * D_ * 2;
    u16* Vt    = (u16*)ws; ws += (size_t)M_ * D_ * 2;
    u16* Ob    = (u16*)ws; ws += (size_t)M_ * D_ * 2;

    prep_kernel<<<8192, 256, 0, stream>>>(x, w_qkv, w_out, Xb, WqkvT, WoutT);
    // QKV: 256x256 tile, 8 waves, 4-phase pipelined K-loop (T3+T4)
    gemm_qkv<<<dim3(M_/256, 3*D_/256), 512, 0, stream>>>(
        Xb, WqkvT, b_qkv, Qb, Kb, Vt);
    attn_kernel<<<1024, 256, 0, stream>>>(Qb, Kb, Vt, Ob);
    // out-proj: 128x128 tile, 4 waves, round-1 counted-vmcnt structure
    gemm_bt2<1, 128, 128, 2, 2, 256><<<dim3(M_/128, D_/128), 256, 0, stream>>>(
        Ob, WoutT, b_out, out, M_, D_, D_);
}

// Round 3
// 171.385 us; speedup vs baseline: 1.0676x; 1.0160x over previous
//
#include <hip/hip_runtime.h>
#include <math.h>

#define B_  2
#define T_  2048
#define D_  1024
#define H_  16
#define HS_ 64
#define M_  (B_*T_)   // 4096

typedef __bf16 bf16x8 __attribute__((ext_vector_type(8)));
typedef float  f32x4  __attribute__((ext_vector_type(4)));
typedef unsigned short u16;

// native HW cvt (v_cvt_pk_bf16_f32 when paired) — RNE, 1 inst vs 3-4 manual
static __device__ __forceinline__ u16 f2bf(float f) {
    __bf16 h = (__bf16)f;
    return *reinterpret_cast<u16*>(&h);
}

// async global->LDS, 16B/lane; LDS dest is lane-linear (base + lane*16).
static __device__ __forceinline__ void glds16(const u16* g, u16* l) {
    __builtin_amdgcn_global_load_lds(
        (const __attribute__((address_space(1))) void*)g,
        (__attribute__((address_space(3))) void*)l, 16, 0, 0);
}

// ---------------- fused prep: cast x, transpose+cast both weights ----------
__global__ __launch_bounds__(256) void prep_kernel(
    const float* __restrict__ x, const float* __restrict__ w_qkv,
    const float* __restrict__ w_out,
    u16* __restrict__ Xb, u16* __restrict__ WqkvT, u16* __restrict__ WoutT)
{
    int bid = blockIdx.x;
    if (bid < 4096) {                       // cast x
        int i = (bid * 256 + threadIdx.x) * 4;
        float4 v = *reinterpret_cast<const float4*>(x + i);
        ushort4 o;
        o.x = f2bf(v.x); o.y = f2bf(v.y); o.z = f2bf(v.z); o.w = f2bf(v.w);
        *reinterpret_cast<ushort4*>(Xb + i) = o;
        return;
    }
    const float* in; u16* out; int C; int c0, r0;
    if (bid < 4096 + 3072) {                // w_qkv (D x 3D) -> (3D x D)
        int t = bid - 4096;
        in = w_qkv; out = WqkvT; C = 3 * D_;
        c0 = (t % 96) * 32; r0 = (t / 96) * 32;
    } else {                                // w_out (D x D) -> (D x D)
        int t = bid - 7168;
        in = w_out; out = WoutT; C = D_;
        c0 = (t & 31) * 32; r0 = (t >> 5) * 32;
    }
    __shared__ float tile[32][33];
    int tr = threadIdx.x >> 3, tc4 = (threadIdx.x & 7) * 4;
    float4 v = *reinterpret_cast<const float4*>(in + (size_t)(r0 + tr) * C + c0 + tc4);
    tile[tr][tc4+0] = v.x; tile[tr][tc4+1] = v.y;
    tile[tr][tc4+2] = v.z; tile[tr][tc4+3] = v.w;
    __syncthreads();
    ushort4 o;
    o.x = f2bf(tile[tc4+0][tr]); o.y = f2bf(tile[tc4+1][tr]);
    o.z = f2bf(tile[tc4+2][tr]); o.w = f2bf(tile[tc4+3][tr]);
    *reinterpret_cast<ushort4*>(out + (size_t)(c0 + tr) * D_ + r0 + tc4) = o;
}

// ---------------- QKV GEMM: 4-phase-per-K-tile pipeline (unchanged R2) -----
__global__ __launch_bounds__(512, 2) void gemm_qkv(
    const u16* __restrict__ A, const u16* __restrict__ Bt,
    const float* __restrict__ bias,
    u16* __restrict__ Qb, u16* __restrict__ Kb, u16* __restrict__ Vt)
{
    constexpr int K  = D_;        // 1024
    constexpr int NT = K / 64;    // 16

    __shared__ u16 LDS[2][2][2][8192];  // [buf][A|B][khalf][256r x 32k swz] = 128 KiB

    const int tid  = threadIdx.x;
    const int lane = tid & 63, wave = tid >> 6;
    const int wm = wave >> 2, wn = wave & 3;       // 2 x 4
    const int quad = lane >> 4, lr = lane & 15;
    const int bm = blockIdx.x, bn = blockIdx.y;

    const u16* Ab = A  + (size_t)(bm * 256) * K;
    const u16* Bb = Bt + (size_t)(bn * 256) * K;

    const int r0 = tid >> 2;
    const int c0 = (tid & 3) ^ ((tid >> 3) & 3);
    const u16* sA0 = Ab + (size_t)r0 * K + c0 * 8;
    const u16* sA1 = sA0 + (size_t)128 * K;
    const u16* sB0 = Bb + (size_t)r0 * K + c0 * 8;
    const u16* sB1 = sB0 + (size_t)128 * K;
    const int d0 = tid * 8, d1 = (tid + 512) * 8;

    const int swz = (lr >> 1) & 3;
    const int eA = ((wm*128 + lr) * 4 + (quad ^ swz)) * 8;
    const int eB = ((wn*64  + lr) * 4 + (quad ^ swz)) * 8;

    f32x4 acc[8][4] = {};

#define STG(mat, kh, tt) do { \
        u16* _d = &LDS[(tt) & 1][mat][kh][0]; \
        const int _ko = (tt) * 64 + (kh) * 32; \
        glds16(((mat) ? sB0 : sA0) + _ko, _d + d0); \
        glds16(((mat) ? sB1 : sA1) + _ko, _d + d1); \
    } while (0)

#define MFMA_QUAD(mh) do { \
        __builtin_amdgcn_s_setprio(1); \
        _Pragma("unroll") \
        for (int i_ = 0; i_ < 4; ++i_) \
            _Pragma("unroll") \
            for (int j_ = 0; j_ < 4; ++j_) \
                acc[(mh)*4 + i_][j_] = __builtin_amdgcn_mfma_f32_16x16x32_bf16( \
                    a[i_], b[j_], acc[(mh)*4 + i_][j_], 0, 0, 0); \
        __builtin_amdgcn_s_setprio(0); \
    } while (0)

    STG(0,0,0); STG(1,0,0); STG(0,1,0); STG(1,1,0);
    asm volatile("s_waitcnt vmcnt(4)" ::: "memory");
    __builtin_amdgcn_s_barrier();

    for (int t = 0; t < NT; ++t) {
        const int cb = t & 1;
        const bool last = (t == NT - 1);
        const u16* Ar0 = &LDS[cb][0][0][0];
        const u16* Ar1 = &LDS[cb][0][1][0];
        const u16* Br0 = &LDS[cb][1][0][0];
        const u16* Br1 = &LDS[cb][1][1][0];
        bf16x8 a[4], b[4];

        // ---- phase A: k0, m-frags 0-3 (+ b k0) ----
        #pragma unroll
        for (int i = 0; i < 4; ++i) a[i] = *reinterpret_cast<const bf16x8*>(Ar0 + eA + i*512);
        #pragma unroll
        for (int j = 0; j < 4; ++j) b[j] = *reinterpret_cast<const bf16x8*>(Br0 + eB + j*512);
        if (!last) STG(0,0,t+1);
        __builtin_amdgcn_s_barrier();
        asm volatile("s_waitcnt lgkmcnt(0)" ::: "memory");
        MFMA_QUAD(0);
        __builtin_amdgcn_s_barrier();

        // ---- phase B: k0, m-frags 4-7 (b reused) ----
        #pragma unroll
        for (int i = 0; i < 4; ++i) a[i] = *reinterpret_cast<const bf16x8*>(Ar0 + eA + (i+4)*512);
        if (!last) STG(1,0,t+1);
        __builtin_amdgcn_s_barrier();
        asm volatile("s_waitcnt lgkmcnt(0)" ::: "memory");
        MFMA_QUAD(1);
        if (!last) { asm volatile("s_waitcnt vmcnt(4)" ::: "memory"); }
        else       { asm volatile("s_waitcnt vmcnt(0)" ::: "memory"); }
        __builtin_amdgcn_s_barrier();

        // ---- phase C: k1, m-frags 0-3 (+ b k1) ----
        #pragma unroll
        for (int i = 0; i < 4; ++i) a[i] = *reinterpret_cast<const bf16x8*>(Ar1 + eA + i*512);
        #pragma unroll
        for (int j = 0; j < 4; ++j) b[j] = *reinterpret_cast<const bf16x8*>(Br1 + eB + j*512);
        if (!last) STG(0,1,t+1);
        __builtin_amdgcn_s_barrier();
        asm volatile("s_waitcnt lgkmcnt(0)" ::: "memory");
        MFMA_QUAD(0);
        __builtin_amdgcn_s_barrier();

        // ---- phase D: k1, m-frags 4-7 ----
        #pragma unroll
        for (int i = 0; i < 4; ++i) a[i] = *reinterpret_cast<const bf16x8*>(Ar1 + eA + (i+4)*512);
        if (!last) STG(1,1,t+1);
        __builtin_amdgcn_s_barrier();
        asm volatile("s_waitcnt lgkmcnt(0)" ::: "memory");
        MFMA_QUAD(1);
        asm volatile("s_waitcnt vmcnt(4)" ::: "memory");
        __builtin_amdgcn_s_barrier();
    }
#undef STG
#undef MFMA_QUAD

    // -------- epilogue: scatter to Q (scale folded) / K / V^T --------
    #pragma unroll
    for (int i = 0; i < 8; ++i) {
        int m0 = bm*256 + wm*128 + i*16 + quad*4;   // 4-aligned
        #pragma unroll
        for (int j = 0; j < 4; ++j) {
            int ncol = bn*256 + wn*64 + j*16 + lr;
            float bv = bias[ncol];
            float v4[4];
            #pragma unroll
            for (int r = 0; r < 4; ++r) v4[r] = acc[i][j][r] + bv;
            int bb = m0 >> 11, t0 = m0 & (T_ - 1);
            int s = ncol >> 10, rem = ncol & 1023;
            int h = rem >> 6, d = rem & 63;
            int bh = bb * H_ + h;
            if (s == 0) {
                // fold softmax scale AND log2(e) (attn uses exp2): 0.125*log2e
                #pragma unroll
                for (int r = 0; r < 4; ++r)
                    Qb[((size_t)bh*T_ + t0 + r)*HS_ + d] = f2bf(v4[r] * 0.1803368801111244f);
            } else if (s == 1) {
                #pragma unroll
                for (int r = 0; r < 4; ++r)
                    Kb[((size_t)bh*T_ + t0 + r)*HS_ + d] = f2bf(v4[r]);
            } else {
                ushort4 o;   // consecutive t -> one 8B store
                o.x = f2bf(v4[0]); o.y = f2bf(v4[1]);
                o.z = f2bf(v4[2]); o.w = f2bf(v4[3]);
                *reinterpret_cast<ushort4*>(&Vt[((size_t)bh*HS_ + d)*T_ + t0]) = o;
            }
        }
    }
}

// ---------------- out-proj GEMM: 2-phase-per-K-tile pipeline, 2 blk/CU -----
// 128x128 tile, BK=64, 4 waves (2M x 2N, 64x64/wave), 256 thr, 64 KiB LDS
// (2 dbuf x {A,B} x k-half regions of 8 KB) -> 2 blocks/CU co-resident:
// one block's barrier/drain overlaps the other's MFMA.
// Per K-tile, 2 phases (one per k-half), each:
//   {8 ds_read_b128 | stage one k-half of t+1 (4 glds) | bar | lgkm0 |
//    setprio(1) 16 MFMA setprio(0) | vmcnt(4) | bar}
// vmcnt(4) retires the k-half needed one phase later; 4-8 loads in flight,
// never drained in the main loop. Same chunk-XOR swizzle (0 conflicts, R0).
__global__ __launch_bounds__(256, 2) void gemm_out(
    const u16* __restrict__ A, const u16* __restrict__ Bt,
    const float* __restrict__ bias, float* __restrict__ Cf)
{
    constexpr int K  = D_;        // 1024
    constexpr int N  = D_;
    constexpr int NT = K / 64;    // 16

    __shared__ u16 LDS[2][2][2][4096];  // [buf][A|B][khalf][128r x 32k swz] = 64 KiB

    const int tid  = threadIdx.x;
    const int lane = tid & 63, wave = tid >> 6;
    const int wm = wave >> 1, wn = wave & 1;       // 2 x 2
    const int quad = lane >> 4, lr = lane & 15;
    const int bm = blockIdx.x, bn = blockIdx.y;

    const u16* Ab = A  + (size_t)(bm * 128) * K;
    const u16* Bb = Bt + (size_t)(bn * 128) * K;

    // staging: region (128r x 32k) = 512 chunks; thread covers {tid, tid+256}
    const int r0 = tid >> 2;
    const int c0 = (tid & 3) ^ ((tid >> 3) & 3);
    const u16* sA0 = Ab + (size_t)r0 * K + c0 * 8;
    const u16* sA1 = sA0 + (size_t)64 * K;
    const u16* sB0 = Bb + (size_t)r0 * K + c0 * 8;
    const u16* sB1 = sB0 + (size_t)64 * K;
    const int d0 = tid * 8, d1 = (tid + 256) * 8;

    const int swz = (lr >> 1) & 3;
    const int eA = ((wm*64 + lr) * 4 + (quad ^ swz)) * 8;
    const int eB = ((wn*64 + lr) * 4 + (quad ^ swz)) * 8;

    f32x4 acc[4][4] = {};

#define STGO(kh, tt) do { \
        const int _ko = (tt) * 64 + (kh) * 32; \
        glds16(sA0 + _ko, &LDS[(tt) & 1][0][kh][0] + d0); \
        glds16(sA1 + _ko, &LDS[(tt) & 1][0][kh][0] + d1); \
        glds16(sB0 + _ko, &LDS[(tt) & 1][1][kh][0] + d0); \
        glds16(sB1 + _ko, &LDS[(tt) & 1][1][kh][0] + d1); \
    } while (0)

    // prologue: stage tile 0 (both k-halves); k0 must land, k1 stays in flight
    STGO(0, 0); STGO(1, 0);
    asm volatile("s_waitcnt vmcnt(4)" ::: "memory");
    __builtin_amdgcn_s_barrier();

    for (int t = 0; t < NT; ++t) {
        const int cb = t & 1;
        const bool last = (t == NT - 1);
        bf16x8 a[4], b[4];

        // ---- phase 0: k-half 0 ----
        {
            const u16* Ar = &LDS[cb][0][0][0];
            const u16* Br = &LDS[cb][1][0][0];
            #pragma unroll
            for (int i = 0; i < 4; ++i) a[i] = *reinterpret_cast<const bf16x8*>(Ar + eA + i*512);
            #pragma unroll
            for (int j = 0; j < 4; ++j) b[j] = *reinterpret_cast<const bf16x8*>(Br + eB + j*512);
            if (!last) STGO(0, t+1);
            __builtin_amdgcn_s_barrier();
            asm volatile("s_waitcnt lgkmcnt(0)" ::: "memory");
            __builtin_amdgcn_s_setprio(1);
            #pragma unroll
            for (int i = 0; i < 4; ++i)
                #pragma unroll
                for (int j = 0; j < 4; ++j)
                    acc[i][j] = __builtin_amdgcn_mfma_f32_16x16x32_bf16(a[i], b[j], acc[i][j], 0, 0, 0);
            __builtin_amdgcn_s_setprio(0);
            // retire k1[t] (needed next phase); keep k0[t+1] flying
            if (!last) { asm volatile("s_waitcnt vmcnt(4)" ::: "memory"); }
            else       { asm volatile("s_waitcnt vmcnt(0)" ::: "memory"); }
            __builtin_amdgcn_s_barrier();
        }

        // ---- phase 1: k-half 1 ----
        {
            const u16* Ar = &LDS[cb][0][1][0];
            const u16* Br = &LDS[cb][1][1][0];
            #pragma unroll
            for (int i = 0; i < 4; ++i) a[i] = *reinterpret_cast<const bf16x8*>(Ar + eA + i*512);
            #pragma unroll
            for (int j = 0; j < 4; ++j) b[j] = *reinterpret_cast<const bf16x8*>(Br + eB + j*512);
            if (!last) STGO(1, t+1);
            __builtin_amdgcn_s_barrier();
            asm volatile("s_waitcnt lgkmcnt(0)" ::: "memory");
            __builtin_amdgcn_s_setprio(1);
            #pragma unroll
            for (int i = 0; i < 4; ++i)
                #pragma unroll
                for (int j = 0; j < 4; ++j)
                    acc[i][j] = __builtin_amdgcn_mfma_f32_16x16x32_bf16(a[i], b[j], acc[i][j], 0, 0, 0);
            __builtin_amdgcn_s_setprio(0);
            // retire k0[t+1] (needed next phase); keep k1[t+1] flying
            if (!last) { asm volatile("s_waitcnt vmcnt(4)" ::: "memory"); }
            __builtin_amdgcn_s_barrier();
        }
    }
#undef STGO

    // -------- epilogue: coalesced f32 rows --------
    #pragma unroll
    for (int i = 0; i < 4; ++i) {
        int m0 = bm*128 + wm*64 + i*16 + quad*4;
        #pragma unroll
        for (int j = 0; j < 4; ++j) {
            int ncol = bn*128 + wn*64 + j*16 + lr;
            float bv = bias[ncol];
            #pragma unroll
            for (int r = 0; r < 4; ++r)
                Cf[(size_t)(m0 + r) * N + ncol] = acc[i][j][r] + bv;
        }
    }
}

// ---------------- Flash attention (causal), bf16 MFMA ----------------
// 1024 blocks x 256 thr. Unchanged this round.
__global__ __launch_bounds__(256) void attn_kernel(
    const u16* __restrict__ Qb, const u16* __restrict__ Kb,
    const u16* __restrict__ Vt, u16* __restrict__ Ob)
{
    __shared__ u16 Ks[64 * 64];        // [key][d], swizzled chunks, 8 KB
    __shared__ u16 Vs[64 * 64];        // [d][key], swizzled chunks, 8 KB
    __shared__ u16 Ps[4][16 * 64];     // per-wave P (16 q x 64 key), swizzled

    int tid  = threadIdx.x;
    int lane = tid & 63, wave = tid >> 6;          // wave 0..3
    int quad = lane >> 4, lr = lane & 15;

    int lin = blockIdx.x;                          // 1024 blocks
    int bh  = (lin & 7) + 8 * ((lin >> 3) & 3);    // XCD-local bh
    int idx = lin >> 5;                            // 0..31
    int qt  = idx < 16 ? idx : 47 - idx;           // balanced pair mapping
    int qw  = qt * 64 + wave * 16;                 // wave's 16 query rows

    // Q fragments (A-layout); 1/sqrt(HS)*log2e pre-folded upstream
    const u16* Qp = Qb + ((size_t)bh * T_ + qw) * HS_;
    bf16x8 qf[2];
    #pragma unroll
    for (int h2 = 0; h2 < 2; ++h2)
        qf[h2] = *reinterpret_cast<const bf16x8*>(Qp + lr*HS_ + h2*32 + quad*8);

    f32x4 Oa[4] = {};
    float lrow[4] = {0.f, 0.f, 0.f, 0.f};

    // ---- loop-invariant LDS addresses (u16-element offsets) ----
    int e      = quad ^ (lr & 7);
    int rb0    = (lr * 8 + e) * 8;          // kk=0 base (chunk-slot*8 u16)
    int rb1    = (lr * 8 + (e ^ 4)) * 8;    // kk=1 base
    int offw[4][4];
    #pragma unroll
    for (int nt = 0; nt < 4; ++nt)
        #pragma unroll
        for (int r = 0; r < 4; ++r) {
            int prow = quad*4 + r;
            offw[nt][r] = (prow*8 + ((nt*2 + (lr >> 3)) ^ (prow & 7)))*8 + (lr & 7);
        }
    u16* Psw = Ps[wave];

    // staging: 256 thr x 2 chunks per matrix; swizzle via source redirect
    int srow = tid >> 3;
    int scol = ((tid & 7) ^ (srow & 7)) * 8;
    const u16* kp0 = Kb + ((size_t)bh*T_ + srow     )*HS_ + scol;
    const u16* kp1 = Kb + ((size_t)bh*T_ + srow + 32)*HS_ + scol;
    const u16* vp0 = Vt + ((size_t)bh*HS_ + srow     )*T_ + scol;
    const u16* vp1 = Vt + ((size_t)bh*HS_ + srow + 32)*T_ + scol;

    bf16x8 kpre0 = *reinterpret_cast<const bf16x8*>(kp0);
    bf16x8 kpre1 = *reinterpret_cast<const bf16x8*>(kp1);
    bf16x8 vpre0 = *reinterpret_cast<const bf16x8*>(vp0);
    bf16x8 vpre1 = *reinterpret_cast<const bf16x8*>(vp1);

    for (int jt = 0; jt <= qt; ++jt) {
        __syncthreads();
        reinterpret_cast<bf16x8*>(Ks)[tid]       = kpre0;
        reinterpret_cast<bf16x8*>(Ks)[tid + 256] = kpre1;
        reinterpret_cast<bf16x8*>(Vs)[tid]       = vpre0;
        reinterpret_cast<bf16x8*>(Vs)[tid + 256] = vpre1;
        if (jt < qt) {
            kp0 += 64*HS_; kp1 += 64*HS_; vp0 += 64; vp1 += 64;
            kpre0 = *reinterpret_cast<const bf16x8*>(kp0);
            kpre1 = *reinterpret_cast<const bf16x8*>(kp1);
            vpre0 = *reinterpret_cast<const bf16x8*>(vp0);
            vpre1 = *reinterpret_cast<const bf16x8*>(vp1);
        }
        __syncthreads();

        // S = Q @ K^T
        f32x4 Sa[4] = {};
        #pragma unroll
        for (int nt = 0; nt < 4; ++nt) {
            bf16x8 bk0 = *reinterpret_cast<const bf16x8*>(Ks + rb0 + nt*1024);
            bf16x8 bk1 = *reinterpret_cast<const bf16x8*>(Ks + rb1 + nt*1024);
            Sa[nt] = __builtin_amdgcn_mfma_f32_16x16x32_bf16(qf[0], bk0, Sa[nt], 0, 0, 0);
            Sa[nt] = __builtin_amdgcn_mfma_f32_16x16x32_bf16(qf[1], bk1, Sa[nt], 0, 0, 0);
        }

        if (jt == qt) {   // causal mask in diagonal tile
            int kb = jt * 64;
            #pragma unroll
            for (int nt = 0; nt < 4; ++nt)
                #pragma unroll
                for (int r = 0; r < 4; ++r) {
                    int kg = kb + nt*16 + lr;
                    int qg = qw + quad*4 + r;
                    if (kg > qg) Sa[nt][r] = -INFINITY;
                }
        }

        // P = exp2(S); per-lane row sums; P -> LDS
        #pragma unroll
        for (int nt = 0; nt < 4; ++nt)
            #pragma unroll
            for (int r = 0; r < 4; ++r) {
                float pv = __builtin_amdgcn_exp2f(Sa[nt][r]);
                lrow[r] += pv;
                Psw[offw[nt][r]] = f2bf(pv);
            }

        // O += P @ V  (same-wave LDS ordering via lgkmcnt; no barrier)
        #pragma unroll
        for (int kk = 0; kk < 2; ++kk) {
            int rb = kk ? rb1 : rb0;
            bf16x8 pa = *reinterpret_cast<const bf16x8*>(Psw + rb);
            #pragma unroll
            for (int nt = 0; nt < 4; ++nt) {
                bf16x8 vb = *reinterpret_cast<const bf16x8*>(Vs + rb + nt*1024);
                Oa[nt] = __builtin_amdgcn_mfma_f32_16x16x32_bf16(pa, vb, Oa[nt], 0, 0, 0);
            }
        }
    }

    // epilogue: reduce row sums across 16 col-lanes, normalize, store
    int b = bh >> 4, h = bh & 15;
    #pragma unroll
    for (int r = 0; r < 4; ++r) {
        float s = lrow[r];
        #pragma unroll
        for (int off = 8; off >= 1; off >>= 1)
            s += __shfl_xor(s, off, 64);
        float inv = 1.f / s;
        int qg = qw + quad*4 + r;
        #pragma unroll
        for (int nt = 0; nt < 4; ++nt) {
            int d = nt*16 + lr;
            Ob[((size_t)b*T_ + qg)*D_ + h*HS_ + d] = f2bf(Oa[nt][r] * inv);
        }
    }
}

extern "C" void kernel_launch(void* const* d_in, const int* in_sizes, int n_in,
                              void* d_out, int out_size, void* d_ws, size_t ws_size,
                              hipStream_t stream) {
    (void)in_sizes; (void)n_in; (void)out_size; (void)ws_size;
    const float* x     = (const float*)d_in[0];
    const float* w_qkv = (const float*)d_in[1];
    const float* b_qkv = (const float*)d_in[2];
    const float* w_out = (const float*)d_in[3];
    const float* b_out = (const float*)d_in[4];
    float* out = (float*)d_out;

    char* ws = (char*)d_ws;
    u16* Xb    = (u16*)ws; ws += (size_t)M_ * D_ * 2;
    u16* WqkvT = (u16*)ws; ws += (size_t)3 * D_ * D_ * 2;
    u16* WoutT = (u16*)ws; ws += (size_t)D_ * D_ * 2;
    u16* Qb    = (u16*)ws; ws += (size_t)M_ * D_ * 2;
    u16* Kb    = (u16*)ws; ws += (size_t)M_ * D_ * 2;
    u16* Vt    = (u16*)ws; ws += (size_t)M_ * D_ * 2;
    u16* Ob    = (u16*)ws; ws += (size_t)M_ * D_ * 2;

    prep_kernel<<<8192, 256, 0, stream>>>(x, w_qkv, w_out, Xb, WqkvT, WoutT);
    gemm_qkv<<<dim3(M_/256, 3*D_/256), 512, 0, stream>>>(
        Xb, WqkvT, b_qkv, Qb, Kb, Vt);
    attn_kernel<<<1024, 256, 0, stream>>>(Qb, Kb, Vt, Ob);
    // out-proj: 128x128, 2-phase pipelined, 256 blocks at 2 blocks/CU
    gemm_out<<<dim3(M_/128, D_/128), 256, 0, stream>>>(Ob, WoutT, b_out, out);
}